// Round 9
// baseline (20472.781 us; speedup 1.0000x reference)
//
#include <hip/hip_runtime.h>

// ---------------------------------------------------------------------------
// RevRNN persistent kernel, round 12 = round 11 RESUBMIT (infra-flake probe,
// zero semantic change; r9->r10 precedent: identical resubmit passed).
// r7 skeleton (14.76ms best) + 16-WG geometry + sticky per-word poll:
// - 16 WGs = 4 batch-groups x 4 col-groups; each WG owns 64 o-cols, W frags
//   doubled to ~256 VGPR/thread (launch_bounds(256,1) -> 512 cap). MFMAs/
//   phase double (issue ~100cy, noise vs ~8600cy phase). Poll traffic and
//   straggler fan halve; state fan-in 8->4 producers per cell.
// - Sticky per-word poll: reload ONLY stale-tag words (monotone tags + the
//   partial fan-in WAR argument make kept words safe). ~2x less LLC traffic.
// - Everything else = r7 verbatim: register xf prefetch (compiler-sunk),
//   __syncthreads barriers, merged tagged-u64 poll+load, fire-and-forget
//   publish, consumer-side centering, branch-free tanh, sticky alive guard.
// Audit notes (r11): no hang path (sticky guard, uniform barriers); VGPR
// resident ~330 < 512 cap; r7->2-subgroup index port re-verified.
// ---------------------------------------------------------------------------

#define T_TOT 2056
#define S_SEQ 2048

typedef _Float16 f16x8 __attribute__((ext_vector_type(8)));
typedef float f32x4 __attribute__((ext_vector_type(4)));

// exchange arrays: static device globals (no workspace-size dependency)
__device__ unsigned long long g_st0[8192];  // [64 rows][128 colpair cells]
__device__ unsigned long long g_st1[8192];
__device__ unsigned long long g_pa0[1024];  // [256 ocol][4 b-groups]
__device__ unsigned long long g_pa1[1024];

__global__ void init_ws() {
  const int i = (int)blockIdx.x * 256 + (int)threadIdx.x;  // 8192 threads
  g_st0[i] = 0ull;
  g_st1[i] = 0ull;
  if (i < 1024) { g_pa0[i] = 0ull; g_pa1[i] = 0ull; }
}

#define AL(P) __hip_atomic_load((P), __ATOMIC_RELAXED, __HIP_MEMORY_SCOPE_AGENT)
#define AS(P, V)                                                               \
  __hip_atomic_store((P), (V), __ATOMIC_RELAXED, __HIP_MEMORY_SCOPE_AGENT)

#define TAGOK(Q) ((unsigned)((Q) >> 32) >= tg_)

// One phase: sticky merged poll(4 partials + 8 state u64) -> LDS -> barrier
// -> centered MFMA (x2 col-subgroups) -> gate -> tagged publish -> barrier.
#define PHASE(SIN, PIN, TAGIN, WS, SOUT, POUT, TAGOUT, RAW)                    \
  {                                                                            \
    const unsigned long long* pp_ = (PIN) + 4 * tid;                           \
    const unsigned long long* sp_ =                                            \
        (SIN) + (size_t)(16 * b + n) * 128 + (2 * wv) * 16 + kq * 4;           \
    const unsigned tg_ = (unsigned)(TAGIN);                                    \
    unsigned long long q0_ = AL(pp_ + 0), q1_ = AL(pp_ + 1),                   \
                       q2_ = AL(pp_ + 2), q3_ = AL(pp_ + 3);                   \
    unsigned long long s0_ = AL(sp_ + 0), s1_ = AL(sp_ + 1),                   \
                       s2_ = AL(sp_ + 2), s3_ = AL(sp_ + 3),                   \
                       s4_ = AL(sp_ + 16), s5_ = AL(sp_ + 17),                 \
                       s6_ = AL(sp_ + 18), s7_ = AL(sp_ + 19);                 \
    int it_ = 0;                                                               \
    for (;;) {                                                                 \
      if (TAGOK(q0_) && TAGOK(q1_) && TAGOK(q2_) && TAGOK(q3_) &&              \
          TAGOK(s0_) && TAGOK(s1_) && TAGOK(s2_) && TAGOK(s3_) &&              \
          TAGOK(s4_) && TAGOK(s5_) && TAGOK(s6_) && TAGOK(s7_))                \
        break;                                                                 \
      if (!alive || ++it_ > (1 << 16)) { alive = 0; break; }                   \
      /* sticky: reload ONLY stale words (exec-masked, less LLC traffic) */    \
      if (!TAGOK(q0_)) q0_ = AL(pp_ + 0);                                      \
      if (!TAGOK(q1_)) q1_ = AL(pp_ + 1);                                      \
      if (!TAGOK(q2_)) q2_ = AL(pp_ + 2);                                      \
      if (!TAGOK(q3_)) q3_ = AL(pp_ + 3);                                      \
      if (!TAGOK(s0_)) s0_ = AL(sp_ + 0);                                      \
      if (!TAGOK(s1_)) s1_ = AL(sp_ + 1);                                      \
      if (!TAGOK(s2_)) s2_ = AL(sp_ + 2);                                      \
      if (!TAGOK(s3_)) s3_ = AL(sp_ + 3);                                      \
      if (!TAGOK(s4_)) s4_ = AL(sp_ + 16);                                     \
      if (!TAGOK(s5_)) s5_ = AL(sp_ + 17);                                     \
      if (!TAGOK(s6_)) s6_ = AL(sp_ + 18);                                     \
      if (!TAGOK(s7_)) s7_ = AL(sp_ + 19);                                     \
    }                                                                          \
    const float mean_ = (__uint_as_float((unsigned)q0_) +                      \
                         __uint_as_float((unsigned)q1_) +                      \
                         __uint_as_float((unsigned)q2_) +                      \
                         __uint_as_float((unsigned)q3_)) * 0.015625f;          \
    mean_h[tid] = (_Float16)mean_;                                             \
    {                                                                          \
      unsigned long long* lp_ =                                                \
          (unsigned long long*)&lds_s[n][(2 * wv) * 16 + kq * 4];              \
      lp_[0] = ((unsigned long long)(unsigned)s1_ << 32) | (unsigned)s0_;      \
      lp_[1] = ((unsigned long long)(unsigned)s3_ << 32) | (unsigned)s2_;      \
      lp_[8] = ((unsigned long long)(unsigned)s5_ << 32) | (unsigned)s4_;      \
      lp_[9] = ((unsigned long long)(unsigned)s7_ << 32) | (unsigned)s6_;      \
    }                                                                          \
    __syncthreads();                                                           \
    _Pragma("unroll")                                                          \
    for (int kk = 0; kk < 8; ++kk) {                                           \
      const f16x8 sv_ = *(const f16x8*)&lds_s[n][kk * 16 + kq * 4];            \
      const f16x8 mv_ = *(const f16x8*)&mean_h[kk * 32 + kq * 8];              \
      const f16x8 av_ = sv_ - mv_;                                             \
      _Pragma("unroll")                                                        \
      for (int g = 0; g < 2; ++g) {                                            \
        if (kk & 1)                                                            \
          acc1[g] = __builtin_amdgcn_mfma_f32_16x16x32_f16(av_, (WS)[g][kk],   \
                                                           acc1[g], 0, 0, 0); \
        else                                                                   \
          acc0[g] = __builtin_amdgcn_mfma_f32_16x16x32_f16(av_, (WS)[g][kk],   \
                                                           acc0[g], 0, 0, 0); \
      }                                                                        \
    }                                                                          \
    _Pragma("unroll")                                                          \
    for (int g = 0; g < 2; ++g) {                                              \
      float nv_[4], ssum_ = 0.f;                                               \
      _Pragma("unroll")                                                        \
      for (int r = 0; r < 4; ++r) {                                            \
        const float z = acc0[g][r] + acc1[g][r];                               \
        const float p = __shfl_xor(z, 8);                                      \
        const float z0 = (n < 8) ? z : p;                                      \
        const float z1 = (n < 8) ? p : z;                                      \
        const float z1c = fminf(fmaxf(z1, -10.f), 10.f);                       \
        const float e2 = __expf(2.f * z1c);                                    \
        const float th = (e2 - 1.f) * __builtin_amdgcn_rcpf(e2 + 1.f);         \
        const float cv = fminf(fmaxf(z0, 0.f), 6.f) * th;                      \
        const float o = ((RAW)[g][r] + cv) * 0.5f;                             \
        (RAW)[g][r] = o; nv_[r] = o; ssum_ += o;                               \
      }                                                                        \
      ssum_ += __shfl_xor(ssum_, 16);                                          \
      ssum_ += __shfl_xor(ssum_, 32);                                          \
      const int ocg_ = ocol0 + g * 8;                                          \
      _Pragma("unroll")                                                        \
      for (int r = 0; r < 4; ++r) {                                            \
        union { _Float16 h; unsigned short u; } hb_;                           \
        hb_.h = (_Float16)nv_[r];                                              \
        const unsigned pr_ = (unsigned)__shfl_xor((int)hb_.u, 1) & 0xFFFFu;    \
        if ((n & 1) == 0 && n < 8) {                                           \
          const unsigned dw_ = (unsigned)hb_.u | (pr_ << 16);                  \
          AS((SOUT) + (size_t)(16 * b + kq * 4 + r) * 128 + (ocg_ >> 1),       \
             ((unsigned long long)(unsigned)(TAGOUT) << 32) |                  \
                 (unsigned long long)dw_);                                     \
        }                                                                      \
      }                                                                        \
      if (kq == 0 && n < 8)                                                    \
        AS((POUT) + (size_t)ocg_ * 4 + b,                                      \
           ((unsigned long long)(unsigned)(TAGOUT) << 32) |                    \
               (unsigned long long)__float_as_uint(ssum_));                    \
    }                                                                          \
    __syncthreads(); /* protect lds_s/mean_h before next phase's fill */       \
  }

__launch_bounds__(256, 1)
__global__ void rnn_kernel(const float* __restrict__ xg,
                           const float* __restrict__ hs,
                           const float* __restrict__ W0,
                           const float* __restrict__ W1,
                           float* __restrict__ out) {
  const int wgid = (int)blockIdx.x;        // 0..15
  const int b = wgid & 3;                  // batch group: rows 16b..16b+15
  const int c = wgid >> 2;                 // col group: o-cols 64c..64c+63
  const int tid = (int)threadIdx.x;
  const int wv = tid >> 6;                 // wave 0..3
  const int ln = tid & 63;
  const int n = ln & 15;                   // packed col in tile / A-row
  const int kq = ln >> 4;                  // quad 0..3
  const int ocol0 = c * 64 + wv * 16 + (n & 7);   // col-subgroup g adds g*8

  __shared__ __align__(16) unsigned lds_s[16][132];   // state payload, padded
  __shared__ __align__(16) _Float16 mean_h[256];

  // ---- preload W fragments: 2 col-subgroups x (state + x parts) ----
  f16x8 w0s[2][8], w0x[2][8], w1s[2][8], w1x[2][8];
  float w0pa[2], w0pb[2], w1pa[2], w1pb[2];
#pragma unroll
  for (int g = 0; g < 2; ++g) {
    const int ocg = ocol0 + g * 8;
    const int wrow = (n < 8) ? ocg : (256 + ocg);
    const float* r0 = W0 + (size_t)wrow * 514;
    const float* r1 = W1 + (size_t)wrow * 514;
#pragma unroll
    for (int kk = 0; kk < 8; ++kk) {
      const int k0 = kk * 32 + kq * 8;
      f16x8 a, bx, a1, bx1;
#pragma unroll
      for (int j = 0; j < 8; ++j) {
        a[j]   = (_Float16)r0[k0 + j];
        bx[j]  = (_Float16)r0[256 + k0 + j];
        a1[j]  = (_Float16)r1[k0 + j];
        bx1[j] = (_Float16)r1[256 + k0 + j];
      }
      w0s[g][kk] = a; w0x[g][kk] = bx; w1s[g][kk] = a1; w1x[g][kk] = bx1;
    }
    w0pa[g] = r0[512]; w0pb[g] = r0[513];
    w1pa[g] = r1[512]; w1pb[g] = r1[513];
  }

  // ---- raw recurrence state (fp32, register-resident) ----
  float raw0[2][4], raw1[2][4];
#pragma unroll
  for (int g = 0; g < 2; ++g)
#pragma unroll
    for (int r = 0; r < 4; ++r) {
      raw0[g][r] = hs[ocol0 + g * 8];
      raw1[g][r] = hs[256 + ocol0 + g * 8];
    }

  int alive = 1;

  // ---- init publish: tagged uncentered h0 pairs + tagged partials, tag 1.
#pragma unroll
  for (int g = 0; g < 2; ++g) {
    const int ocg = ocol0 + g * 8;
    union { _Float16 h; unsigned short u; } e0, e1;
    e0.h = (_Float16)hs[ocg]; e1.h = (_Float16)hs[ocg + 1];
    const unsigned dw = (unsigned)e0.u | ((unsigned)e1.u << 16);
    if ((n & 1) == 0 && n < 8) {
#pragma unroll
      for (int r = 0; r < 4; ++r)
        AS(g_st0 + (size_t)(16 * b + kq * 4 + r) * 128 + (ocg >> 1),
           (1ull << 32) | (unsigned long long)dw);
    }
    if (kq == 0 && n < 8)
      AS(g_pa0 + (size_t)ocg * 4 + b,
         (1ull << 32) | (unsigned long long)__float_as_uint(16.f * hs[ocg]));
  }

  // ---- x prefetch for t=0 (compiler may sink; proven fine in r7) ----
  f32x4 xf[16];
  f16x8 xa[8];
  const int arow = 16 * b + n;
  {
    const float* xp = xg + (size_t)arow * S_SEQ * 256 + kq * 8;
#pragma unroll
    for (int kk = 0; kk < 8; ++kk) {
      xf[2 * kk]     = *(const f32x4*)(xp + kk * 32);
      xf[2 * kk + 1] = *(const f32x4*)(xp + kk * 32 + 4);
    }
  }

  for (int t = 0; t < T_TOT; ++t) {
    const float pe0 = (float)(t + 1);
    const float pe1 = (pe0 - 1028.5f) * (1.0f / 1028.5f);
    const int have_x = (t < S_SEQ);

    // ---------------- phase A: o1 = (h1 + calc(h0c, s, W0)) * 0.5 ----------
    {
      f32x4 acc0[2], acc1[2];
#pragma unroll
      for (int g = 0; g < 2; ++g) {
        const float pt = pe0 * w0pa[g] + pe1 * w0pb[g];
        acc0[g][0] = pt; acc0[g][1] = pt; acc0[g][2] = pt; acc0[g][3] = pt;
        acc1[g][0] = 0.f; acc1[g][1] = 0.f; acc1[g][2] = 0.f; acc1[g][3] = 0.f;
      }
      // x part BEFORE the poll: overlaps the spin / off the critical path.
      if (have_x) {
#pragma unroll
        for (int kk = 0; kk < 8; ++kk) {
          f16x8 af;
#pragma unroll
          for (int j = 0; j < 4; ++j) {
            af[j]     = (_Float16)xf[2 * kk][j];
            af[4 + j] = (_Float16)xf[2 * kk + 1][j];
          }
          xa[kk] = af;
#pragma unroll
          for (int g = 0; g < 2; ++g) {
            if (kk & 1)
              acc1[g] = __builtin_amdgcn_mfma_f32_16x16x32_f16(af, w0x[g][kk],
                                                               acc1[g], 0, 0, 0);
            else
              acc0[g] = __builtin_amdgcn_mfma_f32_16x16x32_f16(af, w0x[g][kk],
                                                               acc0[g], 0, 0, 0);
          }
        }
      }
      PHASE(g_st0, g_pa0, 2 * t + 1, w0s, g_st1, g_pa1, 2 * t + 2, raw1);
    }

    // ---------------- phase B: o0 = (h0 + calc(o1c, s, W1)) * 0.5 ----------
    {
      f32x4 acc0[2], acc1[2];
#pragma unroll
      for (int g = 0; g < 2; ++g) {
        const float pt = pe0 * w1pa[g] + pe1 * w1pb[g];
        acc0[g][0] = pt; acc0[g][1] = pt; acc0[g][2] = pt; acc0[g][3] = pt;
        acc1[g][0] = 0.f; acc1[g][1] = 0.f; acc1[g][2] = 0.f; acc1[g][3] = 0.f;
      }
      if (have_x) {
#pragma unroll
        for (int kk = 0; kk < 8; ++kk) {
#pragma unroll
          for (int g = 0; g < 2; ++g) {
            if (kk & 1)
              acc1[g] = __builtin_amdgcn_mfma_f32_16x16x32_f16(xa[kk],
                                                               w1x[g][kk],
                                                               acc1[g], 0, 0, 0);
            else
              acc0[g] = __builtin_amdgcn_mfma_f32_16x16x32_f16(xa[kk],
                                                               w1x[g][kk],
                                                               acc0[g], 0, 0, 0);
          }
        }
      }
      // prefetch x(t+1): in flight across poll B + phase-A conversion.
      if (t + 1 < S_SEQ) {
        const float* xp = xg + ((size_t)arow * S_SEQ + (t + 1)) * 256 + kq * 8;
#pragma unroll
        for (int kk = 0; kk < 8; ++kk) {
          xf[2 * kk]     = *(const f32x4*)(xp + kk * 32);
          xf[2 * kk + 1] = *(const f32x4*)(xp + kk * 32 + 4);
        }
      }
      PHASE(g_st1, g_pa1, 2 * t + 2, w1s, g_st0, g_pa0, 2 * t + 3, raw0);
    }
  }

  // ---- final h = [o0 | o1] fp32 ----
  if (n < 8) {
#pragma unroll
    for (int g = 0; g < 2; ++g)
#pragma unroll
      for (int r = 0; r < 4; ++r) {
        const int row = 16 * b + kq * 4 + r;
        out[(size_t)row * 512 + ocol0 + g * 8] = raw0[g][r];
        out[(size_t)row * 512 + 256 + ocol0 + g * 8] = raw1[g][r];
      }
  }
}

#undef PHASE
#undef TAGOK
#undef AS
#undef AL

extern "C" void kernel_launch(void* const* d_in, const int* in_sizes, int n_in,
                              void* d_out, int out_size, void* d_ws, size_t ws_size,
                              hipStream_t stream) {
  (void)in_sizes; (void)n_in; (void)out_size; (void)d_ws; (void)ws_size;
  const float* x  = (const float*)d_in[0];
  const float* hs = (const float*)d_in[1];
  const float* W0 = (const float*)d_in[2];
  const float* W1 = (const float*)d_in[3];
  float* out = (float*)d_out;

  // prologue kernel zeroes the tagged exchange globals (stream-ordered;
  // replayed per graph iteration -> tags reset each run). No workspace use.
  init_ws<<<dim3(32), dim3(256), 0, stream>>>();
  rnn_kernel<<<dim3(16), dim3(256), 0, stream>>>(x, hs, W0, W1, out);
}

// Round 10
// 18190.619 us; speedup vs baseline: 1.1255x; 1.1255x over previous
//
#include <hip/hip_runtime.h>

// ---------------------------------------------------------------------------
// RevRNN persistent kernel, round 13 = r7 (best, 14.76ms) + staggered
// double-buffered poll. Single-variable change.
// Evidence: r3/r5/r7 triangulation -> RT ~2k cy, compute ~1k, and ~4-5k
// cy/phase of straggle/detect-quantization (poll samples readiness at RT
// granularity; all-to-all coupling locks the period near max over 32 WGs).
// r12 refuted the congestion theory (fewer pollers = worse), so extra poll
// traffic is acceptable.
// Fix: two full 12-word poll sets per thread, issue offset ~1024cy via
// s_sleep 16 (< RT: off the fast path). Check A (waits only A's regs),
// sticky-reload stale A, check B (in flight, ~RT/2 offset), sticky-reload
// stale B. Detect granularity RT -> ~RT/2; jitter damped. Winner-set copy
// is exec-masked and only taken when B wins (A-win path never waits on B).
// Everything else r7 verbatim: merged self-validating tagged-u64 exchange,
// fire-and-forget publish, consumer-side centering, __syncthreads barriers,
// register xf prefetch, dual MFMA chains, branch-free tanh, sticky guard.
// ---------------------------------------------------------------------------

#define T_TOT 2056
#define S_SEQ 2048

typedef _Float16 f16x8 __attribute__((ext_vector_type(8)));
typedef float f32x4 __attribute__((ext_vector_type(4)));

// exchange arrays: static device globals (no workspace-size dependency)
__device__ unsigned long long g_st0[8192];  // [64 rows][128 colpair cells]
__device__ unsigned long long g_st1[8192];
__device__ unsigned long long g_pa0[1024];  // [256 ocol][4 b-groups]
__device__ unsigned long long g_pa1[1024];

__global__ void init_ws() {
  const int i = (int)blockIdx.x * 256 + (int)threadIdx.x;  // 8192 threads
  g_st0[i] = 0ull;
  g_st1[i] = 0ull;
  if (i < 1024) { g_pa0[i] = 0ull; g_pa1[i] = 0ull; }
}

#define AL(P) __hip_atomic_load((P), __ATOMIC_RELAXED, __HIP_MEMORY_SCOPE_AGENT)
#define AS(P, V)                                                               \
  __hip_atomic_store((P), (V), __ATOMIC_RELAXED, __HIP_MEMORY_SCOPE_AGENT)

#define TOK(Q) ((unsigned)((Q) >> 32) >= tg_)

// One phase: staggered dual-set sticky poll -> LDS -> barrier -> centered
// MFMA -> gate -> tagged publish (fire-and-forget) -> end barrier.
#define PHASE(WS, SIN, PIN, TAGIN, SOUT, POUT, TAGOUT, RAW)                    \
  {                                                                            \
    const unsigned long long* pp_ = (PIN) + 4 * tid;                           \
    const unsigned long long* sp_ =                                            \
        (SIN) + (size_t)(16 * b + n) * 128 + (2 * wv) * 16 + kq * 4;           \
    const unsigned tg_ = (unsigned)(TAGIN);                                    \
    /* set A issue */                                                          \
    unsigned long long qa0_ = AL(pp_ + 0), qa1_ = AL(pp_ + 1),                 \
                       qa2_ = AL(pp_ + 2), qa3_ = AL(pp_ + 3);                 \
    unsigned long long sa0_ = AL(sp_ + 0), sa1_ = AL(sp_ + 1),                 \
                       sa2_ = AL(sp_ + 2), sa3_ = AL(sp_ + 3),                 \
                       sa4_ = AL(sp_ + 16), sa5_ = AL(sp_ + 17),               \
                       sa6_ = AL(sp_ + 18), sa7_ = AL(sp_ + 19);               \
    asm volatile("s_sleep 16" ::: "memory"); /* ~1024cy stagger (< RT) */      \
    /* set B issue, offset ~RT/2 from A */                                     \
    unsigned long long qb0_ = AL(pp_ + 0), qb1_ = AL(pp_ + 1),                 \
                       qb2_ = AL(pp_ + 2), qb3_ = AL(pp_ + 3);                 \
    unsigned long long sb0_ = AL(sp_ + 0), sb1_ = AL(sp_ + 1),                 \
                       sb2_ = AL(sp_ + 2), sb3_ = AL(sp_ + 3),                 \
                       sb4_ = AL(sp_ + 16), sb5_ = AL(sp_ + 17),               \
                       sb6_ = AL(sp_ + 18), sb7_ = AL(sp_ + 19);               \
    asm volatile("" ::: "memory");                                             \
    int useB_ = 0, it_ = 0;                                                    \
    for (;;) {                                                                 \
      /* check A: compiler waits only A's registers; B stays in flight */      \
      if (TOK(qa0_) && TOK(qa1_) && TOK(qa2_) && TOK(qa3_) &&                  \
          TOK(sa0_) && TOK(sa1_) && TOK(sa2_) && TOK(sa3_) &&                  \
          TOK(sa4_) && TOK(sa5_) && TOK(sa6_) && TOK(sa7_)) {                  \
        useB_ = 0; break;                                                      \
      }                                                                        \
      if (!TOK(qa0_)) qa0_ = AL(pp_ + 0);                                      \
      if (!TOK(qa1_)) qa1_ = AL(pp_ + 1);                                      \
      if (!TOK(qa2_)) qa2_ = AL(pp_ + 2);                                      \
      if (!TOK(qa3_)) qa3_ = AL(pp_ + 3);                                      \
      if (!TOK(sa0_)) sa0_ = AL(sp_ + 0);                                      \
      if (!TOK(sa1_)) sa1_ = AL(sp_ + 1);                                      \
      if (!TOK(sa2_)) sa2_ = AL(sp_ + 2);                                      \
      if (!TOK(sa3_)) sa3_ = AL(sp_ + 3);                                      \
      if (!TOK(sa4_)) sa4_ = AL(sp_ + 16);                                     \
      if (!TOK(sa5_)) sa5_ = AL(sp_ + 17);                                     \
      if (!TOK(sa6_)) sa6_ = AL(sp_ + 18);                                     \
      if (!TOK(sa7_)) sa7_ = AL(sp_ + 19);                                     \
      /* check B: samples ~RT/2 after A's sample */                            \
      if (TOK(qb0_) && TOK(qb1_) && TOK(qb2_) && TOK(qb3_) &&                  \
          TOK(sb0_) && TOK(sb1_) && TOK(sb2_) && TOK(sb3_) &&                  \
          TOK(sb4_) && TOK(sb5_) && TOK(sb6_) && TOK(sb7_)) {                  \
        useB_ = 1; break;                                                      \
      }                                                                        \
      if (!TOK(qb0_)) qb0_ = AL(pp_ + 0);                                      \
      if (!TOK(qb1_)) qb1_ = AL(pp_ + 1);                                      \
      if (!TOK(qb2_)) qb2_ = AL(pp_ + 2);                                      \
      if (!TOK(qb3_)) qb3_ = AL(pp_ + 3);                                      \
      if (!TOK(sb0_)) sb0_ = AL(sp_ + 0);                                      \
      if (!TOK(sb1_)) sb1_ = AL(sp_ + 1);                                      \
      if (!TOK(sb2_)) sb2_ = AL(sp_ + 2);                                      \
      if (!TOK(sb3_)) sb3_ = AL(sp_ + 3);                                      \
      if (!TOK(sb4_)) sb4_ = AL(sp_ + 16);                                     \
      if (!TOK(sb5_)) sb5_ = AL(sp_ + 17);                                     \
      if (!TOK(sb6_)) sb6_ = AL(sp_ + 18);                                     \
      if (!TOK(sb7_)) sb7_ = AL(sp_ + 19);                                     \
      if (!alive || ++it_ > (1 << 16)) { alive = 0; break; }                   \
    }                                                                          \
    /* exec-masked winner copy: only taken when B won (no A-path B-wait) */    \
    if (useB_) {                                                               \
      qa0_ = qb0_; qa1_ = qb1_; qa2_ = qb2_; qa3_ = qb3_;                      \
      sa0_ = sb0_; sa1_ = sb1_; sa2_ = sb2_; sa3_ = sb3_;                      \
      sa4_ = sb4_; sa5_ = sb5_; sa6_ = sb6_; sa7_ = sb7_;                      \
    }                                                                          \
    const float mean_ = (__uint_as_float((unsigned)qa0_) +                     \
                         __uint_as_float((unsigned)qa1_) +                     \
                         __uint_as_float((unsigned)qa2_) +                     \
                         __uint_as_float((unsigned)qa3_)) * 0.015625f;         \
    mean_h[tid] = (_Float16)mean_;                                             \
    {                                                                          \
      unsigned long long* lp_ =                                                \
          (unsigned long long*)&lds_s[n][(2 * wv) * 16 + kq * 4];              \
      lp_[0] = ((unsigned long long)(unsigned)sa1_ << 32) | (unsigned)sa0_;    \
      lp_[1] = ((unsigned long long)(unsigned)sa3_ << 32) | (unsigned)sa2_;    \
      lp_[8] = ((unsigned long long)(unsigned)sa5_ << 32) | (unsigned)sa4_;    \
      lp_[9] = ((unsigned long long)(unsigned)sa7_ << 32) | (unsigned)sa6_;    \
    }                                                                          \
    __syncthreads();                                                           \
    _Pragma("unroll")                                                          \
    for (int kk = 0; kk < 8; ++kk) {                                           \
      const f16x8 sv_ = *(const f16x8*)&lds_s[n][kk * 16 + kq * 4];            \
      const f16x8 mv_ = *(const f16x8*)&mean_h[kk * 32 + kq * 8];              \
      if (kk & 1)                                                              \
        acc1 = __builtin_amdgcn_mfma_f32_16x16x32_f16(sv_ - mv_, (WS)[kk],     \
                                                      acc1, 0, 0, 0);          \
      else                                                                     \
        acc0 = __builtin_amdgcn_mfma_f32_16x16x32_f16(sv_ - mv_, (WS)[kk],     \
                                                      acc0, 0, 0, 0);          \
    }                                                                          \
    float nv_[4], ssum_ = 0.f;                                                 \
    _Pragma("unroll")                                                          \
    for (int r = 0; r < 4; ++r) {                                              \
      const float z = acc0[r] + acc1[r];                                       \
      const float p = __shfl_xor(z, 8);                                        \
      const float z0 = (n < 8) ? z : p;                                        \
      const float z1 = (n < 8) ? p : z;                                        \
      /* branch-free tanh: clamp +-10, (e-1)/(e+1); err << f16 quantization */ \
      const float z1c = fminf(fmaxf(z1, -10.f), 10.f);                         \
      const float e2 = __expf(2.f * z1c);                                      \
      const float th = (e2 - 1.f) * __builtin_amdgcn_rcpf(e2 + 1.f);           \
      const float cv = fminf(fmaxf(z0, 0.f), 6.f) * th;                        \
      const float o = ((RAW)[r] + cv) * 0.5f;                                  \
      (RAW)[r] = o; nv_[r] = o; ssum_ += o;                                    \
    }                                                                          \
    ssum_ += __shfl_xor(ssum_, 16);                                            \
    ssum_ += __shfl_xor(ssum_, 32);                                            \
    _Pragma("unroll")                                                          \
    for (int r = 0; r < 4; ++r) {                                              \
      union { _Float16 h; unsigned short u; } hb_;                             \
      hb_.h = (_Float16)nv_[r];                                                \
      const unsigned pr_ = (unsigned)__shfl_xor((int)hb_.u, 1) & 0xFFFFu;      \
      if ((n & 1) == 0 && n < 8) {                                             \
        const unsigned dw_ = (unsigned)hb_.u | (pr_ << 16);                    \
        AS((SOUT) + (size_t)(16 * b + kq * 4 + r) * 128 + (ocol >> 1),         \
           ((unsigned long long)(unsigned)(TAGOUT) << 32) |                    \
               (unsigned long long)dw_);                                       \
      }                                                                        \
    }                                                                          \
    if (kq == 0 && n < 8)                                                      \
      AS((POUT) + (size_t)ocol * 4 + b,                                        \
         ((unsigned long long)(unsigned)(TAGOUT) << 32) |                      \
             (unsigned long long)__float_as_uint(ssum_));                      \
    __syncthreads(); /* protect lds_s/mean_h before next phase's fill */       \
  }

__launch_bounds__(256, 1)
__global__ void rnn_kernel(const float* __restrict__ xg,
                           const float* __restrict__ hs,
                           const float* __restrict__ W0,
                           const float* __restrict__ W1,
                           float* __restrict__ out) {
  const int wgid = (int)blockIdx.x;        // 0..31
  const int b = wgid & 3;                  // batch group: rows 16b..16b+15
  const int c = wgid >> 2;                 // col group: o-cols 32c..32c+31
  const int tid = (int)threadIdx.x;
  const int wv = tid >> 6;                 // wave 0..3
  const int ln = tid & 63;
  const int n = ln & 15;                   // packed col in tile / A-row
  const int kq = ln >> 4;                  // quad 0..3
  const int ocol = c * 32 + wv * 8 + (n & 7);      // owned output column
  const int wrow = (n < 8) ? ocol : (256 + ocol);  // packed W row (z0|z1)

  __shared__ __align__(16) unsigned lds_s[16][132];   // state payload, padded
  __shared__ __align__(16) _Float16 mean_h[256];

  // ---- preload W fragments (state part + x part) into registers ----
  f16x8 w0s[8], w0x[8], w1s[8], w1x[8];
  float w0pa, w0pb, w1pa, w1pb;
  {
    const float* r0 = W0 + (size_t)wrow * 514;
    const float* r1 = W1 + (size_t)wrow * 514;
#pragma unroll
    for (int kk = 0; kk < 8; ++kk) {
      const int k0 = kk * 32 + kq * 8;
      f16x8 a, bx, a1, bx1;
#pragma unroll
      for (int j = 0; j < 8; ++j) {
        a[j]   = (_Float16)r0[k0 + j];
        bx[j]  = (_Float16)r0[256 + k0 + j];
        a1[j]  = (_Float16)r1[k0 + j];
        bx1[j] = (_Float16)r1[256 + k0 + j];
      }
      w0s[kk] = a; w0x[kk] = bx; w1s[kk] = a1; w1x[kk] = bx1;
    }
    w0pa = r0[512]; w0pb = r0[513];
    w1pa = r1[512]; w1pb = r1[513];
  }

  // ---- raw recurrence state (fp32, register-resident) ----
  float raw0[4], raw1[4];
#pragma unroll
  for (int r = 0; r < 4; ++r) { raw0[r] = hs[ocol]; raw1[r] = hs[256 + ocol]; }

  int alive = 1;

  // ---- init publish: tagged uncentered h0 pairs + tagged partials, tag 1.
  {
    union { _Float16 h; unsigned short u; } e0, e1;
    e0.h = (_Float16)hs[ocol]; e1.h = (_Float16)hs[ocol + 1];
    const unsigned dw = (unsigned)e0.u | ((unsigned)e1.u << 16);
    if ((n & 1) == 0 && n < 8) {
#pragma unroll
      for (int r = 0; r < 4; ++r)
        AS(g_st0 + (size_t)(16 * b + kq * 4 + r) * 128 + (ocol >> 1),
           (1ull << 32) | (unsigned long long)dw);
    }
    if (kq == 0 && n < 8)
      AS(g_pa0 + (size_t)ocol * 4 + b,
         (1ull << 32) |
             (unsigned long long)__float_as_uint(16.f * hs[ocol]));
  }

  // ---- x prefetch for t=0 ----
  f32x4 xf[16];
  f16x8 xa[8];
  const int arow = 16 * b + n;
  {
    const float* xp = xg + (size_t)arow * S_SEQ * 256 + kq * 8;
#pragma unroll
    for (int kk = 0; kk < 8; ++kk) {
      xf[2 * kk]     = *(const f32x4*)(xp + kk * 32);
      xf[2 * kk + 1] = *(const f32x4*)(xp + kk * 32 + 4);
    }
  }

  for (int t = 0; t < T_TOT; ++t) {
    const float pe0 = (float)(t + 1);
    const float pe1 = (pe0 - 1028.5f) * (1.0f / 1028.5f);
    const int have_x = (t < S_SEQ);

    // ---------------- phase A: o1 = (h1 + calc(h0c, s, W0)) * 0.5 ----------
    {
      f32x4 acc0, acc1;
      const float pt = pe0 * w0pa + pe1 * w0pb;
      acc0[0] = pt; acc0[1] = pt; acc0[2] = pt; acc0[3] = pt;
      acc1[0] = 0.f; acc1[1] = 0.f; acc1[2] = 0.f; acc1[3] = 0.f;
      // x part BEFORE the poll: overlaps the spin / off the critical path.
      if (have_x) {
#pragma unroll
        for (int kk = 0; kk < 8; ++kk) {
          f16x8 af;
#pragma unroll
          for (int j = 0; j < 4; ++j) {
            af[j]     = (_Float16)xf[2 * kk][j];
            af[4 + j] = (_Float16)xf[2 * kk + 1][j];
          }
          xa[kk] = af;
          if (kk & 1)
            acc1 = __builtin_amdgcn_mfma_f32_16x16x32_f16(af, w0x[kk], acc1,
                                                          0, 0, 0);
          else
            acc0 = __builtin_amdgcn_mfma_f32_16x16x32_f16(af, w0x[kk], acc0,
                                                          0, 0, 0);
        }
      }
      PHASE(w0s, g_st0, g_pa0, 2 * t + 1, g_st1, g_pa1, 2 * t + 2, raw1);
    }

    // ---------------- phase B: o0 = (h0 + calc(o1c, s, W1)) * 0.5 ----------
    {
      f32x4 acc0, acc1;
      const float pt = pe0 * w1pa + pe1 * w1pb;
      acc0[0] = pt; acc0[1] = pt; acc0[2] = pt; acc0[3] = pt;
      acc1[0] = 0.f; acc1[1] = 0.f; acc1[2] = 0.f; acc1[3] = 0.f;
      if (have_x) {
#pragma unroll
        for (int kk = 0; kk < 8; ++kk) {
          if (kk & 1)
            acc1 = __builtin_amdgcn_mfma_f32_16x16x32_f16(xa[kk], w1x[kk],
                                                          acc1, 0, 0, 0);
          else
            acc0 = __builtin_amdgcn_mfma_f32_16x16x32_f16(xa[kk], w1x[kk],
                                                          acc0, 0, 0, 0);
        }
      }
      // prefetch x(t+1): in flight across poll B + phase-A conversion.
      if (t + 1 < S_SEQ) {
        const float* xp = xg + ((size_t)arow * S_SEQ + (t + 1)) * 256 + kq * 8;
#pragma unroll
        for (int kk = 0; kk < 8; ++kk) {
          xf[2 * kk]     = *(const f32x4*)(xp + kk * 32);
          xf[2 * kk + 1] = *(const f32x4*)(xp + kk * 32 + 4);
        }
      }
      PHASE(w1s, g_st1, g_pa1, 2 * t + 2, g_st0, g_pa0, 2 * t + 3, raw0);
    }
  }

  // ---- final h = [o0 | o1] fp32 ----
  if (n < 8) {
#pragma unroll
    for (int r = 0; r < 4; ++r) {
      const int row = 16 * b + kq * 4 + r;
      out[(size_t)row * 512 + ocol] = raw0[r];
      out[(size_t)row * 512 + 256 + ocol] = raw1[r];
    }
  }
}

#undef PHASE
#undef TOK
#undef AS
#undef AL

extern "C" void kernel_launch(void* const* d_in, const int* in_sizes, int n_in,
                              void* d_out, int out_size, void* d_ws, size_t ws_size,
                              hipStream_t stream) {
  (void)in_sizes; (void)n_in; (void)out_size; (void)d_ws; (void)ws_size;
  const float* x  = (const float*)d_in[0];
  const float* hs = (const float*)d_in[1];
  const float* W0 = (const float*)d_in[2];
  const float* W1 = (const float*)d_in[3];
  float* out = (float*)d_out;

  // prologue kernel zeroes the tagged exchange globals (stream-ordered;
  // replayed per graph iteration -> tags reset each run). No workspace use.
  init_ws<<<dim3(32), dim3(256), 0, stream>>>();
  rnn_kernel<<<dim3(32), dim3(256), 0, stream>>>(x, hs, W0, W1, out);
}